// Round 2
// baseline (450.452 us; speedup 1.0000x reference)
//
#include <hip/hip_runtime.h>

// TemporalXORReservoirNetwork — v3: linear-reconstruction + fill-shaped streamer.
//
// With zero spikes (threshold ~8 sigma above the V distribution), V is LINEAR
// in x:  V(t,b,n) = sum_j Win[n][j] * Xj(t,b),  Xj(t,b) = beta-scan of x[:,b,j].
// A per-row bound  sum_j |Xj(t,b)| * max_n|Win[n][j]|  < 1  proves an entire
// (t,b) row of 2048 neurons is spike-free WITHOUT per-element work, so the
// 419 MB spk_rec write degenerates to a memset (the poison fills demonstrate
// 6.2 TB/s on this very buffer with this shape).
//
//   A: wmax(Win) + 768 beta-scans -> rowbound[51200], Xscan[51200][3], flag=0
//   B: grid-stride float4 zero-store (fill-shaped); rows with bound >= 0.999
//      get an exact 12-fma spike check -> atomicOr(flag)
//   C: flag==0 -> immediate exit; else full coupled resim (verified fallback)
//
// Speculation is exact: true dynamics == linear dynamics up to and including
// the FIRST spike, so B cannot miss the first spike; any spike -> C rewrites
// everything (spk_rec + logits) with the exact coupled simulation.

#define SEQ    200
#define BATCH  256
#define NRES   2048
#define BETA_F 0.9f
#define NROW   (SEQ * BATCH)                       // 51200 rows
#define SPK_FLOATS ((size_t)SEQ * BATCH * NRES)    // 104,857,600
#define LOGITS 512                                 // 256*2 logits floats
// ws layout (floats): [0] int flag | [64, 64+NROW) rowbound | [64+NROW, 64+4*NROW) Xscan
#define WS_FLOATS (64 + NROW + 3 * NROW)

// ---------------------------------------------------------------------------
// Kernel A: per-(b,j) beta-scan + per-row spike bound. 4 blocks x 256 threads.
// ---------------------------------------------------------------------------
__global__ __launch_bounds__(256) void scan_kernel(
    const float* __restrict__ x,     // [200, 256, 3]
    const float* __restrict__ Win,   // [2048, 3]
    float* __restrict__ ws)
{
    __shared__ float swm[4][3];
    __shared__ float wm[3];
    const int tid  = threadIdx.x;
    const int lane = tid & 63;
    const int wv   = tid >> 6;

    // max_n |Win[n][j]| for j=0,1,2 (redundant per block; 24 KB read)
    float p0 = 0.f, p1 = 0.f, p2 = 0.f;
    for (int n = tid; n < NRES; n += 256) {
        const float* r = Win + (size_t)n * 3;
        p0 = fmaxf(p0, fabsf(r[0]));
        p1 = fmaxf(p1, fabsf(r[1]));
        p2 = fmaxf(p2, fabsf(r[2]));
    }
    #pragma unroll
    for (int off = 32; off; off >>= 1) {
        p0 = fmaxf(p0, __shfl_down(p0, off));
        p1 = fmaxf(p1, __shfl_down(p1, off));
        p2 = fmaxf(p2, __shfl_down(p2, off));
    }
    if (lane == 0) { swm[wv][0] = p0; swm[wv][1] = p1; swm[wv][2] = p2; }
    __syncthreads();
    if (tid == 0) {
        wm[0] = fmaxf(fmaxf(swm[0][0], swm[1][0]), fmaxf(swm[2][0], swm[3][0]));
        wm[1] = fmaxf(fmaxf(swm[0][1], swm[1][1]), fmaxf(swm[2][1], swm[3][1]));
        wm[2] = fmaxf(fmaxf(swm[0][2], swm[1][2]), fmaxf(swm[2][2], swm[3][2]));
        if (blockIdx.x == 0) *(int*)ws = 0;   // spike flag (B atomicOr's into it)
    }
    __syncthreads();

    if (tid < 64) {
        const int b = blockIdx.x * 64 + tid;   // 4 blocks x 64 = 256 batch rows
        const float w0 = wm[0], w1 = wm[1], w2 = wm[2];
        float* rowbound = ws + 64;
        float* xs       = ws + 64 + NROW;
        float X0 = 0.f, X1 = 0.f, X2 = 0.f;
        #pragma unroll 4
        for (int t = 0; t < SEQ; ++t) {
            const float* px = x + ((size_t)t * BATCH + b) * 3;
            X0 = fmaf(BETA_F, X0, px[0]);
            X1 = fmaf(BETA_F, X1, px[1]);
            X2 = fmaf(BETA_F, X2, px[2]);
            const int r = t * BATCH + b;
            rowbound[r] = fmaf(fabsf(X0), w0, fmaf(fabsf(X1), w1, fabsf(X2) * w2));
            float* xr = xs + (size_t)r * 3;
            xr[0] = X0; xr[1] = X1; xr[2] = X2;
        }
    }
}

// ---------------------------------------------------------------------------
// Kernel B: fill-shaped zero streamer + rare exact spike check.
// ---------------------------------------------------------------------------
__global__ __launch_bounds__(256) void stream_kernel(
    const float* __restrict__ Win,
    float* __restrict__ out,
    float* __restrict__ ws)
{
    const float* rowbound = ws + 64;
    const float* xs       = ws + 64 + NROW;
    int* flag = (int*)ws;
    const size_t nspk   = SPK_FLOATS / 4;            // 26,214,400 16B chunks
    const size_t nchunk = nspk + LOGITS / 4;         // + logits (zeros if clean)
    const size_t stride = (size_t)gridDim.x * blockDim.x;
    size_t idx = (size_t)blockIdx.x * blockDim.x + threadIdx.x;
    const float4 z = make_float4(0.f, 0.f, 0.f, 0.f);

    for (; idx < nchunk; idx += stride) {
        if (idx < nspk) {
            const int r = (int)(idx >> 9);           // (t*256+b), 512 chunks/row
            const float bnd = rowbound[r];           // wave-broadcast, L1/L2 hit
            if (__builtin_expect(!(bnd < 0.999f), 0)) {
                // bound inconclusive (incl. NaN): exact V for these 4 neurons
                const int n = ((int)idx & 511) << 2;
                const float* X = xs + (size_t)r * 3;
                const float X0 = X[0], X1 = X[1], X2 = X[2];
                const float* wr = Win + (size_t)n * 3;   // 12 contiguous floats
                const float v0 = fmaf(X0, wr[0], fmaf(X1, wr[1],  X2 * wr[2]));
                const float v1 = fmaf(X0, wr[3], fmaf(X1, wr[4],  X2 * wr[5]));
                const float v2 = fmaf(X0, wr[6], fmaf(X1, wr[7],  X2 * wr[8]));
                const float v3 = fmaf(X0, wr[9], fmaf(X1, wr[10], X2 * wr[11]));
                if (!(v0 < 1.f) || !(v1 < 1.f) || !(v2 < 1.f) || !(v3 < 1.f))
                    atomicOr(flag, 1);
            }
        }
        reinterpret_cast<float4*>(out)[idx] = z;     // spikes => C rewrites all
    }
}

// ---------------------------------------------------------------------------
// Kernel C: gate + exact coupled fallback (harness-verified structure).
// ---------------------------------------------------------------------------
#define NTHR 1024

__global__ __launch_bounds__(NTHR, 1) void fallback_kernel(
    const float* __restrict__ x,
    const float* __restrict__ W,
    const float* __restrict__ Win,
    const float* __restrict__ Wout,
    float* __restrict__ out,
    const float* __restrict__ ws)
{
    if (*(const int*)ws == 0) return;   // no spikes: B's zeros are exact

    const int b    = blockIdx.x;
    const int tid  = threadIdx.x;
    const int lane = tid & 63;
    const int wid  = tid >> 6;
    const int n0   = tid << 1;

    __shared__ unsigned long long smask[2][32];
    __shared__ int    scum[2];
    __shared__ float4 sx[SEQ];
    __shared__ float  red[2][16];

    for (int t = tid; t < SEQ; t += NTHR) {
        const float* p = x + (size_t)t * (BATCH * 3) + b * 3;
        sx[t] = make_float4(p[0], p[1], p[2], 0.0f);
    }
    if (tid < 64) smask[tid >> 5][tid & 31] = 0ull;
    if (tid < 2)  scum[tid] = 0;

    const float* wr = Win + (size_t)n0 * 3;
    const float w00 = wr[0], w01 = wr[1], w02 = wr[2];
    const float w10 = wr[3], w11 = wr[4], w12 = wr[5];

    float V0 = 0.f, V1 = 0.f;
    int cnt0 = 0, cnt1 = 0;
    __syncthreads();

    auto step = [&](int t, int cur, int prev, int& seen) {
        float rec0 = 0.f, rec1 = 0.f;
        const int c = scum[prev];
        if (__builtin_expect(c != seen, 0)) {
            seen = c;
            #pragma unroll 1
            for (int u = 0; u < 32; ++u) {
                unsigned long long m = smask[prev][u];
                const int kbase = ((u >> 1) << 7) + (u & 1);
                while (m) {
                    const int l = __builtin_ctzll(m);
                    m &= m - 1;
                    const int k = kbase + (l << 1);
                    const float2 wvv = *(const float2*)(W + (size_t)k * NRES + n0);
                    rec0 += wvv.x;
                    rec1 += wvv.y;
                }
            }
        }
        const float4 xv = sx[t];
        const float i0 = fmaf(xv.x, w00, fmaf(xv.y, w01, xv.z * w02)) + rec0;
        const float i1 = fmaf(xv.x, w10, fmaf(xv.y, w11, xv.z * w12)) + rec1;
        V0 = fmaf(BETA_F, V0, i0);
        V1 = fmaf(BETA_F, V1, i1);
        const bool s0 = (V0 >= 1.0f);
        const bool s1 = (V1 >= 1.0f);
        V0 = s0 ? 0.f : V0;
        V1 = s1 ? 0.f : V1;
        *(float2*)(out + ((size_t)t * BATCH + b) * NRES + n0) =
            make_float2(s0 ? 1.f : 0.f, s1 ? 1.f : 0.f);
        if (t >= SEQ - 10) { cnt0 += (int)s0; cnt1 += (int)s1; }
        const unsigned long long b0 = __ballot(s0);
        const unsigned long long b1 = __ballot(s1);
        if (lane == 0) {
            smask[cur][2 * wid]     = b0;
            smask[cur][2 * wid + 1] = b1;
            const int pc = __popcll(b0) + __popcll(b1);
            if (pc) atomicAdd(&scum[cur], pc);
        }
        asm volatile("s_waitcnt lgkmcnt(0)\n\ts_barrier" ::: "memory");
    };

    int seen0 = 0, seen1 = 0;
    for (int tt = 0; tt < SEQ; tt += 2) {
        step(tt,     0, 1, seen1);
        step(tt + 1, 1, 0, seen0);
    }

    const float a0 = (float)cnt0 * 0.1f;
    const float a1 = (float)cnt1 * 0.1f;
    float p0 = fmaf(a0, Wout[n0], a1 * Wout[n0 + 1]);
    float p1 = fmaf(a0, Wout[NRES + n0], a1 * Wout[NRES + n0 + 1]);
    #pragma unroll
    for (int off = 32; off > 0; off >>= 1) {
        p0 += __shfl_down(p0, off);
        p1 += __shfl_down(p1, off);
    }
    if (lane == 0) { red[0][wid] = p0; red[1][wid] = p1; }
    __syncthreads();
    if (tid == 0) {
        float q0 = 0.f, q1 = 0.f;
        #pragma unroll
        for (int i = 0; i < 16; ++i) { q0 += red[0][i]; q1 += red[1][i]; }
        const size_t loff = SPK_FLOATS;
        out[loff + b * 2 + 0] = q0;
        out[loff + b * 2 + 1] = q1;
    }
}

// ---------------------------------------------------------------------------
// Monolithic fallback (harness-verified v2) for the ws-too-small case.
// ---------------------------------------------------------------------------
__global__ __launch_bounds__(NTHR, 1) void snn_reservoir_kernel(
    const float* __restrict__ x,
    const float* __restrict__ W,
    const float* __restrict__ Win,
    const float* __restrict__ Wout,
    float* __restrict__ out)
{
    const int b    = blockIdx.x;
    const int tid  = threadIdx.x;
    const int lane = tid & 63;
    const int wid  = tid >> 6;
    const int n0   = tid << 1;

    __shared__ unsigned long long smask[2][32];
    __shared__ int    scum[2];
    __shared__ float4 sx[SEQ];
    __shared__ float  red[2][16];
    __shared__ int    sspike;

    for (int t = tid; t < SEQ; t += NTHR) {
        const float* p = x + (size_t)t * (BATCH * 3) + b * 3;
        sx[t] = make_float4(p[0], p[1], p[2], 0.0f);
    }
    if (tid == 0) sspike = 0;

    const float* wr = Win + (size_t)n0 * 3;
    const float w00 = wr[0], w01 = wr[1], w02 = wr[2];
    const float w10 = wr[3], w11 = wr[4], w12 = wr[5];

    __syncthreads();

    float V0 = 0.f, V1 = 0.f;
    bool  any = false;
    unsigned long long* pout =
        (unsigned long long*)(out + (size_t)b * NRES + n0);
    const size_t step_ull = (size_t)BATCH * NRES / 2;

    #pragma unroll 4
    for (int t = 0; t < SEQ; ++t) {
        const float4 xv = sx[t];
        const float i0 = fmaf(xv.x, w00, fmaf(xv.y, w01, xv.z * w02));
        const float i1 = fmaf(xv.x, w10, fmaf(xv.y, w11, xv.z * w12));
        V0 = fmaf(BETA_F, V0, i0);
        V1 = fmaf(BETA_F, V1, i1);
        const bool s0 = (V0 >= 1.0f);
        const bool s1 = (V1 >= 1.0f);
        any |= (s0 | s1);
        V0 = s0 ? 0.f : V0;
        V1 = s1 ? 0.f : V1;
        const unsigned long long wv =
            ((unsigned long long)(s1 ? 0x3f800000u : 0u) << 32) |
            (unsigned long long)(s0 ? 0x3f800000u : 0u);
        __builtin_nontemporal_store(wv, pout);
        pout += step_ull;
    }

    const int wany = __any(any);
    if (wany && lane == 0) atomicOr(&sspike, 1);
    __syncthreads();

    const size_t loff = SPK_FLOATS;
    if (sspike == 0) {
        if (tid == 0) {
            out[loff + b * 2 + 0] = 0.f;
            out[loff + b * 2 + 1] = 0.f;
        }
        return;
    }

    if (tid < 64) smask[tid >> 5][tid & 31] = 0ull;
    if (tid < 2)  scum[tid] = 0;
    V0 = 0.f; V1 = 0.f;
    int cnt0 = 0, cnt1 = 0;
    __syncthreads();

    auto step = [&](int t, int cur, int prev, int& seen) {
        float rec0 = 0.f, rec1 = 0.f;
        const int c = scum[prev];
        if (__builtin_expect(c != seen, 0)) {
            seen = c;
            #pragma unroll 1
            for (int u = 0; u < 32; ++u) {
                unsigned long long m = smask[prev][u];
                const int kbase = ((u >> 1) << 7) + (u & 1);
                while (m) {
                    const int l = __builtin_ctzll(m);
                    m &= m - 1;
                    const int k = kbase + (l << 1);
                    const float2 wvv = *(const float2*)(W + (size_t)k * NRES + n0);
                    rec0 += wvv.x;
                    rec1 += wvv.y;
                }
            }
        }
        const float4 xv = sx[t];
        const float i0 = fmaf(xv.x, w00, fmaf(xv.y, w01, xv.z * w02)) + rec0;
        const float i1 = fmaf(xv.x, w10, fmaf(xv.y, w11, xv.z * w12)) + rec1;
        V0 = fmaf(BETA_F, V0, i0);
        V1 = fmaf(BETA_F, V1, i1);
        const bool s0 = (V0 >= 1.0f);
        const bool s1 = (V1 >= 1.0f);
        V0 = s0 ? 0.f : V0;
        V1 = s1 ? 0.f : V1;
        *(float2*)(out + ((size_t)t * BATCH + b) * NRES + n0) =
            make_float2(s0 ? 1.f : 0.f, s1 ? 1.f : 0.f);
        if (t >= SEQ - 10) { cnt0 += (int)s0; cnt1 += (int)s1; }
        const unsigned long long b0 = __ballot(s0);
        const unsigned long long b1 = __ballot(s1);
        if (lane == 0) {
            smask[cur][2 * wid]     = b0;
            smask[cur][2 * wid + 1] = b1;
            const int pc = __popcll(b0) + __popcll(b1);
            if (pc) atomicAdd(&scum[cur], pc);
        }
        asm volatile("s_waitcnt lgkmcnt(0)\n\ts_barrier" ::: "memory");
    };

    int seen0 = 0, seen1 = 0;
    for (int tt = 0; tt < SEQ; tt += 2) {
        step(tt,     0, 1, seen1);
        step(tt + 1, 1, 0, seen0);
    }

    const float a0 = (float)cnt0 * 0.1f;
    const float a1 = (float)cnt1 * 0.1f;
    float p0 = fmaf(a0, Wout[n0], a1 * Wout[n0 + 1]);
    float p1 = fmaf(a0, Wout[NRES + n0], a1 * Wout[NRES + n0 + 1]);
    #pragma unroll
    for (int off = 32; off > 0; off >>= 1) {
        p0 += __shfl_down(p0, off);
        p1 += __shfl_down(p1, off);
    }
    if (lane == 0) { red[0][wid] = p0; red[1][wid] = p1; }
    __syncthreads();
    if (tid == 0) {
        float q0 = 0.f, q1 = 0.f;
        #pragma unroll
        for (int i = 0; i < 16; ++i) { q0 += red[0][i]; q1 += red[1][i]; }
        out[loff + b * 2 + 0] = q0;
        out[loff + b * 2 + 1] = q1;
    }
}

extern "C" void kernel_launch(void* const* d_in, const int* in_sizes, int n_in,
                              void* d_out, int out_size, void* d_ws, size_t ws_size,
                              hipStream_t stream) {
    const float* x    = (const float*)d_in[0];
    const float* W    = (const float*)d_in[1];
    const float* Win  = (const float*)d_in[2];
    const float* Wout = (const float*)d_in[3];
    float* out = (float*)d_out;

    if (d_ws && ws_size >= (size_t)WS_FLOATS * sizeof(float)) {
        float* ws = (float*)d_ws;
        hipLaunchKernelGGL(scan_kernel,     dim3(4),    dim3(256),  0, stream, x, Win, ws);
        hipLaunchKernelGGL(stream_kernel,   dim3(2048), dim3(256),  0, stream, Win, out, ws);
        hipLaunchKernelGGL(fallback_kernel, dim3(BATCH), dim3(NTHR), 0, stream,
                           x, W, Win, Wout, out, ws);
    } else {
        hipLaunchKernelGGL(snn_reservoir_kernel, dim3(BATCH), dim3(NTHR), 0, stream,
                           x, W, Win, Wout, out);
    }
}

// Round 3
// 408.325 us; speedup vs baseline: 1.1032x; 1.1032x over previous
//
#include <hip/hip_runtime.h>

// TemporalXORReservoirNetwork: 200-step leaky-integrate-and-fire reservoir.
// Batch rows are independent => 1 block per batch element, no grid sync.
// V lives in registers (2 neurons/thread), S[b,:] as a 2048-bit mask in LDS.
// Expected dynamics: no spikes (threshold is ~8 sigma above V distribution),
// so the S@W sparse gather is gated off by a cumulative spike counter and the
// kernel is bound by the 419 MB spk_rec write stream.
//
// NOTE (session decomposition, rounds 0-2): total dur_us is dominated by a
// fixed ~330 us harness component (1.678 GB poison fills at ~265 us visible
// in every rocprof top-5). Three disjoint structures (this one, a
// barrier-free register sim, a fill-shaped zero streamer) measured
// 410/425/450 us — the kernel-side cost of THIS version is ~80 us against a
// 67 us compulsory-write floor (419 MB @ 6.3 TB/s). This is the measured-best
// configuration; structural changes only added launch overhead.

#define SEQ    200
#define BATCH  256
#define NRES   2048
#define NTHR   1024
#define BETA_F 0.9f

__global__ __launch_bounds__(NTHR, 1) void snn_reservoir_kernel(
    const float* __restrict__ x,     // [200, 256, 3]
    const float* __restrict__ W,     // [2048, 2048]  (row k -> col n)
    const float* __restrict__ Win,   // [2048, 3]
    const float* __restrict__ Wout,  // [2, 2048]
    float* __restrict__ out)         // spk_rec [200,256,2048] then logits [256,2]
{
    const int b    = blockIdx.x;
    const int tid  = threadIdx.x;
    const int lane = tid & 63;
    const int wid  = tid >> 6;        // 16 waves
    const int n0   = tid << 1;        // this thread owns neurons n0, n0+1

    // Double-buffered spike bitmask: wave w writes words 2w (even n) / 2w+1 (odd n).
    // Bit l of word 2w   -> n = 128*w + 2*l
    // Bit l of word 2w+1 -> n = 128*w + 2*l + 1
    __shared__ unsigned long long smask[2][32];
    __shared__ int   scum[2];         // cumulative spike count per parity (never reset)
    __shared__ float4 sx[SEQ];        // x[:, b, :] staged once
    __shared__ float red[2][16];

    for (int t = tid; t < SEQ; t += NTHR) {
        const float* p = x + (size_t)t * (BATCH * 3) + b * 3;
        sx[t] = make_float4(p[0], p[1], p[2], 0.0f);
    }
    if (tid < 64) smask[tid >> 5][tid & 31] = 0ull;
    if (tid < 2)  scum[tid] = 0;

    // Per-thread input weights (persist in registers for all 200 steps)
    const float* wr = Win + (size_t)n0 * 3;
    const float w00 = wr[0], w01 = wr[1], w02 = wr[2];
    const float w10 = wr[3], w11 = wr[4], w12 = wr[5];

    float V0 = 0.f, V1 = 0.f;
    int cnt0 = 0, cnt1 = 0;

    __syncthreads();   // full barrier once: staging loads + LDS init visible

    auto step = [&](int t, int cur, int prev, int& seen) {
        float rec0 = 0.f, rec1 = 0.f;
        const int c = scum[prev];
        if (__builtin_expect(c != seen, 0)) {
            // spikes occurred at step t-1: sparse gather of W rows
            seen = c;
            #pragma unroll 1
            for (int u = 0; u < 32; ++u) {
                unsigned long long m = smask[prev][u];
                const int kbase = ((u >> 1) << 7) + (u & 1);
                while (m) {
                    const int l = __builtin_ctzll(m);
                    m &= m - 1;
                    const int k = kbase + (l << 1);
                    const float2 wv = *(const float2*)(W + (size_t)k * NRES + n0);
                    rec0 += wv.x;
                    rec1 += wv.y;
                }
            }
        }
        const float4 xv = sx[t];
        const float i0 = fmaf(xv.x, w00, fmaf(xv.y, w01, xv.z * w02)) + rec0;
        const float i1 = fmaf(xv.x, w10, fmaf(xv.y, w11, xv.z * w12)) + rec1;
        V0 = fmaf(BETA_F, V0, i0);
        V1 = fmaf(BETA_F, V1, i1);
        const bool s0 = (V0 >= 1.0f);
        const bool s1 = (V1 >= 1.0f);
        V0 = s0 ? 0.f : V0;
        V1 = s1 ? 0.f : V1;
        *(float2*)(out + ((size_t)t * BATCH + b) * NRES + n0) =
            make_float2(s0 ? 1.f : 0.f, s1 ? 1.f : 0.f);
        if (t >= SEQ - 10) { cnt0 += (int)s0; cnt1 += (int)s1; }
        const unsigned long long b0 = __ballot(s0);
        const unsigned long long b1 = __ballot(s1);
        if (lane == 0) {
            smask[cur][2 * wid]     = b0;
            smask[cur][2 * wid + 1] = b1;
            const int pc = __popcll(b0) + __popcll(b1);
            if (pc) atomicAdd(&scum[cur], pc);
        }
        // LDS-only barrier: __syncthreads() would emit s_waitcnt vmcnt(0) and
        // drain the spk_rec store stream every step (~800 cy). Only LDS
        // ordering (lgkmcnt) is required for smask/scum correctness.
        asm volatile("s_waitcnt lgkmcnt(0)\n\ts_barrier" ::: "memory");
    };

    int seen0 = 0, seen1 = 0;
    for (int tt = 0; tt < SEQ; tt += 2) {
        step(tt,     0, 1, seen1);   // even t: cur=0, prev=1
        step(tt + 1, 1, 0, seen0);   // odd  t: cur=1, prev=0
    }

    // logits[b, o] = sum_n (cnt[n]/10) * Wout[o, n]
    const float a0 = (float)cnt0 * 0.1f;
    const float a1 = (float)cnt1 * 0.1f;
    float p0 = fmaf(a0, Wout[n0], a1 * Wout[n0 + 1]);
    float p1 = fmaf(a0, Wout[NRES + n0], a1 * Wout[NRES + n0 + 1]);
    #pragma unroll
    for (int off = 32; off > 0; off >>= 1) {
        p0 += __shfl_down(p0, off);
        p1 += __shfl_down(p1, off);
    }
    if (lane == 0) { red[0][wid] = p0; red[1][wid] = p1; }
    __syncthreads();
    if (tid == 0) {
        float q0 = 0.f, q1 = 0.f;
        #pragma unroll
        for (int i = 0; i < 16; ++i) { q0 += red[0][i]; q1 += red[1][i]; }
        const size_t loff = (size_t)SEQ * BATCH * NRES;
        out[loff + b * 2 + 0] = q0;
        out[loff + b * 2 + 1] = q1;
    }
}

extern "C" void kernel_launch(void* const* d_in, const int* in_sizes, int n_in,
                              void* d_out, int out_size, void* d_ws, size_t ws_size,
                              hipStream_t stream) {
    const float* x    = (const float*)d_in[0];
    const float* W    = (const float*)d_in[1];
    const float* Win  = (const float*)d_in[2];
    const float* Wout = (const float*)d_in[3];
    float* out = (float*)d_out;
    hipLaunchKernelGGL(snn_reservoir_kernel, dim3(BATCH), dim3(NTHR), 0, stream,
                       x, W, Win, Wout, out);
}